// Round 1
// baseline (2981.890 us; speedup 1.0000x reference)
//
#include <hip/hip_runtime.h>
#include <math.h>

#define D 128
#define NSTATE 16
#define DR 8
#define T_SEQ 1024
#define NTOK 131072  // 128 sequences * 1024 tokens

__device__ __forceinline__ float sigmoidf_(float x) { return 1.0f / (1.0f + __expf(-x)); }
__device__ __forceinline__ float softplusf_(float x) { return (x > 20.0f) ? x : log1pf(__expf(x)); }

// ---------------- prep kernels ----------------

// src (LB, J, K) -> dst (LB, K, J)
__global__ void k_transpose(const float* __restrict__ src, float* __restrict__ dst,
                            int LB, int J, int K) {
    int idx = blockIdx.x * blockDim.x + threadIdx.x;
    int total = LB * J * K;
    if (idx >= total) return;
    int l = idx / (J * K);
    int rem = idx - l * (J * K);
    int j = rem / K;
    int k = rem - j * K;
    dst[(size_t)l * J * K + (size_t)k * J + j] = src[idx];
}

// A2 = -exp(A_log) * log2(e)
__global__ void k_a2(const float* __restrict__ A_log, float* __restrict__ A2, int total) {
    int idx = blockIdx.x * blockDim.x + threadIdx.x;
    if (idx < total) A2[idx] = -__expf(A_log[idx]) * 1.44269504088896340736f;
}

// h[tok][d] = x[tok] * inp_w[d] + inp_b[d]
__global__ void k_init_h(const float* __restrict__ x, const float* __restrict__ inp_w,
                         const float* __restrict__ inp_b, float* __restrict__ h) {
    int idx = blockIdx.x * blockDim.x + threadIdx.x;
    int tok = idx >> 7;
    int d = idx & 127;
    h[idx] = x[tok] * inp_w[d] + inp_b[d];
}

// ---------------- per-layer kernels ----------------
// Fused LN + in_proj + causal depthwise conv(k=3) + SiLU.
// Block = 256 threads, handles 16 consecutive tokens of one sequence + 2 halo rows.
__global__ __launch_bounds__(256) void k_ln_inproj_conv(
    const float* __restrict__ h, const float* __restrict__ ln_g, const float* __restrict__ ln_b,
    const float* __restrict__ in_wT,  // (128,256): in_wT[k][j] = in_w[j][k]
    const float* __restrict__ conv_w, const float* __restrict__ conv_b,
    float* __restrict__ xc, float* __restrict__ res)
{
    __shared__ float z[18][128];
    const int tid = threadIdx.x;
    const int tstart = blockIdx.x * 16;          // global central token start
    const int tin = tstart & (T_SEQ - 1);        // position within sequence

    // Phase A: LayerNorm (one wave per row, round-robin). Rows with t<0 -> z=0 (xi pad).
    const int wave = tid >> 6, lane = tid & 63;
    for (int r = wave; r < 18; r += 4) {
        int tr = tin + r - 2;
        if (tr < 0) { z[r][lane] = 0.f; z[r][lane + 64] = 0.f; continue; }
        size_t row = (size_t)(tstart + r - 2) * D;
        float a = h[row + lane];
        float b = h[row + lane + 64];
        float s = a + b, ss = a * a + b * b;
        #pragma unroll
        for (int m = 1; m < 64; m <<= 1) { s += __shfl_xor(s, m); ss += __shfl_xor(ss, m); }
        float mu = s * (1.0f / 128.0f);
        float var = ss * (1.0f / 128.0f) - mu * mu;
        float rstd = rsqrtf(var + 1e-5f);
        z[r][lane]      = (a - mu) * rstd * ln_g[lane]      + ln_b[lane];
        z[r][lane + 64] = (b - mu) * rstd * ln_g[lane + 64] + ln_b[lane + 64];
    }
    __syncthreads();

    // Phase B: GEMM column j = tid over 18 rows (z broadcast from LDS, weights coalesced).
    float acc[18];
    #pragma unroll
    for (int r = 0; r < 18; ++r) acc[r] = 0.f;
    for (int k = 0; k < 128; ++k) {
        float w = in_wT[k * 256 + tid];
        #pragma unroll
        for (int r = 0; r < 18; ++r) acc[r] = fmaf(z[r][k], w, acc[r]);
    }

    // Phase C: conv + silu (j<128 -> xc) / raw gate (j>=128 -> res)
    if (tid < 128) {
        float c0 = conv_w[tid * 3 + 0], c1 = conv_w[tid * 3 + 1], c2 = conv_w[tid * 3 + 2];
        float cb = conv_b[tid];
        #pragma unroll
        for (int s = 0; s < 16; ++s) {
            float v = acc[s] * c0 + acc[s + 1] * c1 + acc[s + 2] * c2 + cb;
            v = v * sigmoidf_(v);
            xc[(size_t)(tstart + s) * D + tid] = v;
        }
    } else {
        int jj = tid - 128;
        #pragma unroll
        for (int s = 0; s < 16; ++s)
            res[(size_t)(tstart + s) * D + jj] = acc[s + 2];
    }
}

// x_proj: dbc[t][0..39] = xc[t] @ xp_w.T  (dlt | B | C)
__global__ __launch_bounds__(256) void k_xproj(
    const float* __restrict__ xc, const float* __restrict__ xp_wT, float* __restrict__ dbc)
{
    __shared__ float xcs[32][128];
    const int tid = threadIdx.x;
    const size_t tb = (size_t)blockIdx.x * 32;
    for (int i = tid; i < 32 * 128; i += 256)
        xcs[i >> 7][i & 127] = xc[tb * D + i];
    __syncthreads();
    const int j = tid & 63, rg = tid >> 6;
    if (j < 40) {
        float acc[8] = {0.f, 0.f, 0.f, 0.f, 0.f, 0.f, 0.f, 0.f};
        for (int k = 0; k < 128; ++k) {
            float w = xp_wT[k * 40 + j];
            #pragma unroll
            for (int rr = 0; rr < 8; ++rr) acc[rr] = fmaf(xcs[rg * 8 + rr][k], w, acc[rr]);
        }
        #pragma unroll
        for (int rr = 0; rr < 8; ++rr)
            dbc[(tb + rg * 8 + rr) * 40 + j] = acc[rr];
    }
}

// Selective scan + u*Dp + silu(res) gating. Writes gated y in-place over res.
// Grid: 256 blocks (128 sequences x 2 d-halves). Block: 1024 threads = 64 d x 16 n.
__global__ __launch_bounds__(1024) void k_scan(
    const float* __restrict__ xc, const float* __restrict__ dbc,
    const float* __restrict__ dp_w, const float* __restrict__ dp_b,
    const float* __restrict__ A2, const float* __restrict__ Dp,
    float* __restrict__ res)
{
    __shared__ float u_l[16][64], r_l[16][64], dl_l[16][64], y_l[16][64];
    __shared__ float db_l[16][40];
    __shared__ float dpw_s[64][9];   // padded to 9 to kill bank conflicts
    __shared__ float dpb_s[64];

    const int tid = threadIdx.x;
    const int bt = blockIdx.x >> 1;
    const int d0 = (blockIdx.x & 1) * 64;
    const int dd = tid >> 4, n = tid & 15;
    const int d = d0 + dd;

    if (tid < 512) dpw_s[tid >> 3][tid & 7] = dp_w[(d0 + (tid >> 3)) * 8 + (tid & 7)];
    if (tid < 64) dpb_s[tid] = dp_b[d0 + tid];
    const float A2dn = A2[d * NSTATE + n];
    const float Dpd = Dp[d];
    float xstate = 0.f;
    const int tl_s = tid >> 6, k2 = tid & 63;
    __syncthreads();

    for (int c = 0; c < 64; ++c) {
        const size_t tb = (size_t)bt * T_SEQ + c * 16;
        // stage chunk (16 timesteps)
        u_l[tl_s][k2] = xc[(tb + tl_s) * D + d0 + k2];
        r_l[tl_s][k2] = res[(tb + tl_s) * D + d0 + k2];
        if (tid < 640) {
            int tl = tid / 40, q = tid - tl * 40;
            db_l[tl][q] = dbc[(tb + tl) * 40 + q];
        }
        __syncthreads();
        // delta = softplus(dlt @ dp_w.T + dp_b), one value per thread
        {
            float v = dpb_s[k2];
            #pragma unroll
            for (int r = 0; r < DR; ++r) v = fmaf(db_l[tl_s][r], dpw_s[k2][r], v);
            dl_l[tl_s][k2] = softplusf_(v);
        }
        __syncthreads();
        // 16 sequential steps
        #pragma unroll
        for (int tl = 0; tl < 16; ++tl) {
            float dt = dl_l[tl][dd];
            float u = u_l[tl][dd];
            float Bn = db_l[tl][8 + n];
            float Cn = db_l[tl][24 + n];
            float dA = exp2f(dt * A2dn);
            xstate = fmaf(dA, xstate, dt * Bn * u);
            float p = xstate * Cn;
            p += __shfl_xor(p, 1);
            p += __shfl_xor(p, 2);
            p += __shfl_xor(p, 4);
            p += __shfl_xor(p, 8);
            if (n == 0) {
                float gte = r_l[tl][dd];
                y_l[tl][dd] = (p + u * Dpd) * (gte * sigmoidf_(gte));
            }
        }
        __syncthreads();
        res[(tb + tl_s) * D + d0 + k2] = y_l[tl_s][k2];
        __syncthreads();
    }
}

// out_proj + residual: h[t] += y[t] @ out_w.T
__global__ __launch_bounds__(256) void k_outproj(
    const float* __restrict__ y, const float* __restrict__ out_wT, float* __restrict__ h)
{
    __shared__ float ys[32][128];
    const int tid = threadIdx.x;
    const size_t tb = (size_t)blockIdx.x * 32;
    for (int i = tid; i < 32 * 128; i += 256)
        ys[i >> 7][i & 127] = y[tb * D + i];
    __syncthreads();
    const int j = tid & 127, rg = tid >> 7;
    float acc[16];
    #pragma unroll
    for (int rr = 0; rr < 16; ++rr) acc[rr] = 0.f;
    for (int k = 0; k < 128; ++k) {
        float w = out_wT[k * 128 + j];
        #pragma unroll
        for (int rr = 0; rr < 16; ++rr) acc[rr] = fmaf(ys[rg * 16 + rr][k], w, acc[rr]);
    }
    #pragma unroll
    for (int rr = 0; rr < 16; ++rr) {
        size_t o = (tb + rg * 16 + rr) * D + j;
        h[o] += acc[rr];
    }
}

// out[t] = h[t] . outp_w + outp_b  (one wave per token)
__global__ __launch_bounds__(256) void k_final(
    const float* __restrict__ h, const float* __restrict__ outp_w,
    const float* __restrict__ outp_b, float* __restrict__ out)
{
    const int tid = threadIdx.x;
    const int lane = tid & 63;
    const size_t tok = (size_t)blockIdx.x * 4 + (tid >> 6);
    float a = h[tok * D + lane] * outp_w[lane] + h[tok * D + lane + 64] * outp_w[lane + 64];
    #pragma unroll
    for (int m = 1; m < 64; m <<= 1) a += __shfl_xor(a, m);
    if (lane == 0) out[tok] = a + outp_b[0];
}

extern "C" void kernel_launch(void* const* d_in, const int* in_sizes, int n_in,
                              void* d_out, int out_size, void* d_ws, size_t ws_size,
                              hipStream_t stream)
{
    const float* x      = (const float*)d_in[0];
    const float* inp_w  = (const float*)d_in[1];
    const float* inp_b  = (const float*)d_in[2];
    const float* outp_w = (const float*)d_in[3];
    const float* outp_b = (const float*)d_in[4];
    const float* ln_g   = (const float*)d_in[5];
    const float* ln_b   = (const float*)d_in[6];
    const float* in_w   = (const float*)d_in[7];
    const float* conv_w = (const float*)d_in[8];
    const float* conv_b = (const float*)d_in[9];
    const float* xp_w   = (const float*)d_in[10];
    const float* dp_w   = (const float*)d_in[11];
    const float* dp_b   = (const float*)d_in[12];
    const float* A_log  = (const float*)d_in[13];
    const float* Dp     = (const float*)d_in[14];
    const float* out_w  = (const float*)d_in[15];

    float* ws = (float*)d_ws;
    size_t off = 0;
    float* h      = ws + off; off += (size_t)NTOK * D;
    float* xc     = ws + off; off += (size_t)NTOK * D;
    float* res    = ws + off; off += (size_t)NTOK * D;   // reused as gated y
    float* dbc    = ws + off; off += (size_t)NTOK * 40;
    float* in_wT  = ws + off; off += 4 * 128 * 256;
    float* xp_wT  = ws + off; off += 4 * 40 * 128;
    float* out_wT = ws + off; off += 4 * 128 * 128;
    float* A2     = ws + off; off += 4 * 128 * 16;
    if (ws_size < off * sizeof(float)) return;  // workspace too small -> fail visibly

    // prep (cheap, once per call)
    k_transpose<<<(4 * 256 * 128 + 255) / 256, 256, 0, stream>>>(in_w, in_wT, 4, 256, 128);
    k_transpose<<<(4 * 40 * 128 + 255) / 256, 256, 0, stream>>>(xp_w, xp_wT, 4, 40, 128);
    k_transpose<<<(4 * 128 * 128 + 255) / 256, 256, 0, stream>>>(out_w, out_wT, 4, 128, 128);
    k_a2<<<(4 * 128 * 16 + 255) / 256, 256, 0, stream>>>(A_log, A2, 4 * 128 * 16);
    k_init_h<<<NTOK * D / 256, 256, 0, stream>>>(x, inp_w, inp_b, h);

    for (int l = 0; l < 4; ++l) {
        k_ln_inproj_conv<<<NTOK / 16, 256, 0, stream>>>(
            h, ln_g + l * 128, ln_b + l * 128, in_wT + l * 128 * 256,
            conv_w + l * 128 * 3, conv_b + l * 128, xc, res);
        k_xproj<<<NTOK / 32, 256, 0, stream>>>(xc, xp_wT + l * 128 * 40, dbc);
        k_scan<<<256, 1024, 0, stream>>>(xc, dbc, dp_w + l * 128 * 8, dp_b + l * 128,
                                         A2 + l * 128 * 16, Dp + l * 128, res);
        k_outproj<<<NTOK / 32, 256, 0, stream>>>(res, out_wT + l * 128 * 128, h);
    }
    k_final<<<NTOK / 4, 256, 0, stream>>>(h, outp_w, outp_b, (float*)d_out);
}

// Round 3
// 2687.499 us; speedup vs baseline: 1.1095x; 1.1095x over previous
//
#include <hip/hip_runtime.h>
#include <math.h>

#define D 128
#define NSTATE 16
#define DR 8
#define T_SEQ 1024
#define NTOK 131072  // 128 sequences * 1024 tokens

__device__ __forceinline__ float sigmoidf_(float x) { return 1.0f / (1.0f + __expf(-x)); }
__device__ __forceinline__ float softplusf_(float x) { return (x > 20.0f) ? x : log1pf(__expf(x)); }

// ---------------- prep kernels ----------------

// src (LB, J, K) -> dst (LB, K, J)
__global__ void k_transpose(const float* __restrict__ src, float* __restrict__ dst,
                            int LB, int J, int K) {
    int idx = blockIdx.x * blockDim.x + threadIdx.x;
    int total = LB * J * K;
    if (idx >= total) return;
    int l = idx / (J * K);
    int rem = idx - l * (J * K);
    int j = rem / K;
    int k = rem - j * K;
    dst[(size_t)l * J * K + (size_t)k * J + j] = src[idx];
}

// A2 = -exp(A_log) * log2(e)
__global__ void k_a2(const float* __restrict__ A_log, float* __restrict__ A2, int total) {
    int idx = blockIdx.x * blockDim.x + threadIdx.x;
    if (idx < total) A2[idx] = -__expf(A_log[idx]) * 1.44269504088896340736f;
}

// h[tok][d] = x[tok] * inp_w[d] + inp_b[d]
__global__ void k_init_h(const float* __restrict__ x, const float* __restrict__ inp_w,
                         const float* __restrict__ inp_b, float* __restrict__ h) {
    int idx = blockIdx.x * blockDim.x + threadIdx.x;
    int tok = idx >> 7;
    int d = idx & 127;
    h[idx] = x[tok] * inp_w[d] + inp_b[d];
}

// ---------------- per-layer kernels ----------------
// Fused LN + in_proj + causal depthwise conv(k=3) + SiLU.
// Block = 256 threads, 32 central tokens + 2 halo rows (34 rows x 256 cols).
__global__ __launch_bounds__(256) void k_ln_inproj_conv(
    const float* __restrict__ h, const float* __restrict__ ln_g, const float* __restrict__ ln_b,
    const float* __restrict__ in_wT,  // (128,256): in_wT[k][j] = in_w[j][k]
    const float* __restrict__ conv_w, const float* __restrict__ conv_b,
    float* __restrict__ xc, float* __restrict__ res)
{
    __shared__ float z[34][128];
    const int tid = threadIdx.x;
    const int tstart = blockIdx.x * 32;          // global central token start
    const int tin = tstart & (T_SEQ - 1);        // position within sequence

    // Phase A: LayerNorm (one wave per row, round-robin). Rows with t<0 -> z=0 (xi pad).
    const int wave = tid >> 6, lane = tid & 63;
    for (int r = wave; r < 34; r += 4) {
        int tr = tin + r - 2;
        if (tr < 0) { z[r][lane] = 0.f; z[r][lane + 64] = 0.f; continue; }
        size_t row = (size_t)(tstart + r - 2) * D;
        float a = h[row + lane];
        float b = h[row + lane + 64];
        float s = a + b, ss = a * a + b * b;
        #pragma unroll
        for (int m = 1; m < 64; m <<= 1) { s += __shfl_xor(s, m); ss += __shfl_xor(ss, m); }
        float mu = s * (1.0f / 128.0f);
        float var = ss * (1.0f / 128.0f) - mu * mu;
        float rstd = rsqrtf(var + 1e-5f);
        z[r][lane]      = (a - mu) * rstd * ln_g[lane]      + ln_b[lane];
        z[r][lane + 64] = (b - mu) * rstd * ln_g[lane + 64] + ln_b[lane + 64];
    }
    __syncthreads();

    // Phase B: GEMM column j = tid over 34 rows. z broadcast via float4 LDS reads.
    float acc[34];
    #pragma unroll
    for (int r = 0; r < 34; ++r) acc[r] = 0.f;
    for (int k = 0; k < 128; k += 4) {
        float w0 = in_wT[(k + 0) * 256 + tid];
        float w1 = in_wT[(k + 1) * 256 + tid];
        float w2 = in_wT[(k + 2) * 256 + tid];
        float w3 = in_wT[(k + 3) * 256 + tid];
        #pragma unroll
        for (int r = 0; r < 34; ++r) {
            float4 zv = *(const float4*)&z[r][k];
            float a0 = fmaf(zv.x, w0, acc[r]);
            float a1 = fmaf(zv.y, w1, a0);
            float a2 = fmaf(zv.z, w2, a1);
            acc[r] = fmaf(zv.w, w3, a2);
        }
    }

    // Phase C: conv + silu (j<128 -> xc) / raw gate (j>=128 -> res)
    if (tid < 128) {
        float c0 = conv_w[tid * 3 + 0], c1 = conv_w[tid * 3 + 1], c2 = conv_w[tid * 3 + 2];
        float cb = conv_b[tid];
        #pragma unroll
        for (int s = 0; s < 32; ++s) {
            float v = acc[s] * c0 + acc[s + 1] * c1 + acc[s + 2] * c2 + cb;
            v = v * sigmoidf_(v);
            xc[(size_t)(tstart + s) * D + tid] = v;
        }
    } else {
        int jj = tid - 128;
        #pragma unroll
        for (int s = 0; s < 32; ++s)
            res[(size_t)(tstart + s) * D + jj] = acc[s + 2];
    }
}

// x_proj: per token, dlt[0..7] and bc[0..31] = xc @ xp_w.T split.
__global__ __launch_bounds__(256) void k_xproj(
    const float* __restrict__ xc, const float* __restrict__ xp_wT,
    float* __restrict__ bc, float* __restrict__ dlt)
{
    __shared__ float xcs[32][128];
    const int tid = threadIdx.x;
    const size_t tb = (size_t)blockIdx.x * 32;
    #pragma unroll
    for (int i = 0; i < 4; ++i) {
        int idx = tid + i * 256;           // f4 index: row = idx>>5, c4 = idx&31
        int row = idx >> 5, c4 = idx & 31;
        *(float4*)&xcs[row][c4 * 4] = *(const float4*)&xc[(tb + row) * D + c4 * 4];
    }
    __syncthreads();
    const int j = tid & 63, rg = tid >> 6;
    if (j < 40) {
        float acc[8] = {0.f, 0.f, 0.f, 0.f, 0.f, 0.f, 0.f, 0.f};
        for (int k = 0; k < 128; k += 4) {
            float w0 = xp_wT[(k + 0) * 40 + j];
            float w1 = xp_wT[(k + 1) * 40 + j];
            float w2 = xp_wT[(k + 2) * 40 + j];
            float w3 = xp_wT[(k + 3) * 40 + j];
            #pragma unroll
            for (int rr = 0; rr < 8; ++rr) {
                float4 zv = *(const float4*)&xcs[rg * 8 + rr][k];
                float a0 = fmaf(zv.x, w0, acc[rr]);
                float a1 = fmaf(zv.y, w1, a0);
                float a2 = fmaf(zv.z, w2, a1);
                acc[rr] = fmaf(zv.w, w3, a2);
            }
        }
        if (j < 8) {
            #pragma unroll
            for (int rr = 0; rr < 8; ++rr)
                dlt[(tb + rg * 8 + rr) * 8 + j] = acc[rr];
        } else {
            #pragma unroll
            for (int rr = 0; rr < 8; ++rr)
                bc[(tb + rg * 8 + rr) * 32 + (j - 8)] = acc[rr];
        }
    }
}

// Selective scan, 4 states/thread. Grid: 256 blocks (128 seq x 2 d-halves),
// block 256 threads = 64 d x 4 n-quads. Computes delta in-block, fuses
// u*Dp + silu(res) gating; writes gated y over res (disjoint cols per block).
__global__ __launch_bounds__(256) void k_scan(
    const float* __restrict__ xc, const float* __restrict__ bc,
    const float* __restrict__ dlt,
    const float* __restrict__ dp_w, const float* __restrict__ dp_b,
    const float* __restrict__ A2, const float* __restrict__ Dp,
    float* __restrict__ resy)   // in: gate, out: gated y
{
    __shared__ float u_l[32][64];
    __shared__ float r_l[32][64];
    __shared__ float bc_l[32][32];
    __shared__ float dlt_l[32][8];
    __shared__ float dl_l[32][64];
    __shared__ float y_l[32][64];
    __shared__ float dpw_s[64][9];
    __shared__ float dpb_s[64];

    const int tid = threadIdx.x;
    const int bt = blockIdx.x >> 1;
    const int d0 = (blockIdx.x & 1) * 64;
    const int dd = tid >> 2, q = tid & 3;     // d-channel, n-quad
    const int d = d0 + dd;

    // one-time weights
    #pragma unroll
    for (int i = 0; i < 2; ++i) {
        int idx = tid + i * 256;              // 512 values
        dpw_s[idx >> 3][idx & 7] = dp_w[(d0 + (idx >> 3)) * 8 + (idx & 7)];
    }
    if (tid < 64) dpb_s[tid] = dp_b[d0 + tid];
    float A2q[4];
    #pragma unroll
    for (int jn = 0; jn < 4; ++jn) A2q[jn] = A2[d * NSTATE + q * 4 + jn];
    const float Dpd = Dp[d];
    float x0 = 0.f, x1 = 0.f, x2 = 0.f, x3 = 0.f;

    const size_t seqbase = (size_t)bt * T_SEQ;
    // staging register file (double-buffer vs LDS)
    float4 su0, su1, sr0, sr1, sbc, sdl;
    // preload chunk 0
    {
        const size_t tb = seqbase;
        int v0 = tid, v1 = tid + 256;
        su0 = *(const float4*)&xc[(tb + (v0 >> 4)) * D + d0 + (v0 & 15) * 4];
        su1 = *(const float4*)&xc[(tb + (v1 >> 4)) * D + d0 + (v1 & 15) * 4];
        sr0 = *(const float4*)&resy[(tb + (v0 >> 4)) * D + d0 + (v0 & 15) * 4];
        sr1 = *(const float4*)&resy[(tb + (v1 >> 4)) * D + d0 + (v1 & 15) * 4];
        sbc = *(const float4*)&bc[(tb + (tid >> 3)) * 32 + (tid & 7) * 4];
        if (tid < 64) sdl = *(const float4*)&dlt[(tb + (tid >> 1)) * 8 + (tid & 1) * 4];
    }

    for (int c = 0; c < 32; ++c) {
        const size_t tb = seqbase + (size_t)c * 32;
        // flush y of chunk c-1 (y_l stable since last barrier)
        if (c > 0) {
            const size_t pb = tb - 32;
            int v0 = tid, v1 = tid + 256;
            *(float4*)&resy[(pb + (v0 >> 4)) * D + d0 + (v0 & 15) * 4] = *(const float4*)&y_l[v0 >> 4][(v0 & 15) * 4];
            *(float4*)&resy[(pb + (v1 >> 4)) * D + d0 + (v1 & 15) * 4] = *(const float4*)&y_l[v1 >> 4][(v1 & 15) * 4];
        }
        // stage regs -> LDS
        {
            int v0 = tid, v1 = tid + 256;
            *(float4*)&u_l[v0 >> 4][(v0 & 15) * 4] = su0;
            *(float4*)&u_l[v1 >> 4][(v1 & 15) * 4] = su1;
            *(float4*)&r_l[v0 >> 4][(v0 & 15) * 4] = sr0;
            *(float4*)&r_l[v1 >> 4][(v1 & 15) * 4] = sr1;
            *(float4*)&bc_l[tid >> 3][(tid & 7) * 4] = sbc;
            if (tid < 64) *(float4*)&dlt_l[tid >> 1][(tid & 1) * 4] = sdl;
        }
        __syncthreads();
        // issue loads for chunk c+1 (latency hides under delta-compute + scan)
        if (c + 1 < 32) {
            const size_t nb = tb + 32;
            int v0 = tid, v1 = tid + 256;
            su0 = *(const float4*)&xc[(nb + (v0 >> 4)) * D + d0 + (v0 & 15) * 4];
            su1 = *(const float4*)&xc[(nb + (v1 >> 4)) * D + d0 + (v1 & 15) * 4];
            sr0 = *(const float4*)&resy[(nb + (v0 >> 4)) * D + d0 + (v0 & 15) * 4];
            sr1 = *(const float4*)&resy[(nb + (v1 >> 4)) * D + d0 + (v1 & 15) * 4];
            sbc = *(const float4*)&bc[(nb + (tid >> 3)) * 32 + (tid & 7) * 4];
            if (tid < 64) sdl = *(const float4*)&dlt[(nb + (tid >> 1)) * 8 + (tid & 1) * 4];
        }
        // delta = softplus(dlt @ dp_w.T + dp_b): 8 values per thread
        {
            int row = tid >> 3;
            int cbase = (tid & 7) * 8;
            #pragma unroll
            for (int cc = 0; cc < 8; ++cc) {
                int col = cbase + cc;
                float v = dpb_s[col];
                #pragma unroll
                for (int r = 0; r < DR; ++r) v = fmaf(dlt_l[row][r], dpw_s[col][r], v);
                dl_l[row][col] = softplusf_(v);
            }
        }
        __syncthreads();
        // 32 sequential steps
        #pragma unroll
        for (int tl = 0; tl < 32; ++tl) {
            float dt = dl_l[tl][dd];
            float uv = u_l[tl][dd];
            float duv = dt * uv;
            float4 Bq = *(const float4*)&bc_l[tl][q * 4];
            float4 Cq = *(const float4*)&bc_l[tl][16 + q * 4];
            float e;
            e = exp2f(dt * A2q[0]); x0 = fmaf(e, x0, duv * Bq.x);
            e = exp2f(dt * A2q[1]); x1 = fmaf(e, x1, duv * Bq.y);
            e = exp2f(dt * A2q[2]); x2 = fmaf(e, x2, duv * Bq.z);
            e = exp2f(dt * A2q[3]); x3 = fmaf(e, x3, duv * Bq.w);
            float p = x0 * Cq.x;
            p = fmaf(x1, Cq.y, p);
            p = fmaf(x2, Cq.z, p);
            p = fmaf(x3, Cq.w, p);
            p += __shfl_xor(p, 1);
            p += __shfl_xor(p, 2);
            if (q == 0) {
                float g = r_l[tl][dd];
                y_l[tl][dd] = (p + uv * Dpd) * (g * sigmoidf_(g));
            }
        }
        __syncthreads();
    }
    // flush last chunk
    {
        const size_t pb = seqbase + 31 * 32;
        int v0 = tid, v1 = tid + 256;
        *(float4*)&resy[(pb + (v0 >> 4)) * D + d0 + (v0 & 15) * 4] = *(const float4*)&y_l[v0 >> 4][(v0 & 15) * 4];
        *(float4*)&resy[(pb + (v1 >> 4)) * D + d0 + (v1 & 15) * 4] = *(const float4*)&y_l[v1 >> 4][(v1 & 15) * 4];
    }
}

// out_proj + residual: h[t] += y[t] @ out_w.T   (y already gated)
__global__ __launch_bounds__(256) void k_outproj(
    const float* __restrict__ y, const float* __restrict__ out_wT, float* __restrict__ h)
{
    __shared__ float ys[32][128];
    const int tid = threadIdx.x;
    const size_t tb = (size_t)blockIdx.x * 32;
    #pragma unroll
    for (int i = 0; i < 4; ++i) {
        int idx = tid + i * 256;
        int row = idx >> 5, c4 = idx & 31;
        *(float4*)&ys[row][c4 * 4] = *(const float4*)&y[(tb + row) * D + c4 * 4];
    }
    __syncthreads();
    const int j = tid & 127, rg = tid >> 7;   // 2 groups x 16 rows
    float acc[16];
    #pragma unroll
    for (int rr = 0; rr < 16; ++rr) acc[rr] = 0.f;
    for (int k = 0; k < 128; k += 4) {
        float w0 = out_wT[(k + 0) * 128 + j];
        float w1 = out_wT[(k + 1) * 128 + j];
        float w2 = out_wT[(k + 2) * 128 + j];
        float w3 = out_wT[(k + 3) * 128 + j];
        #pragma unroll
        for (int rr = 0; rr < 16; ++rr) {
            float4 zv = *(const float4*)&ys[rg * 16 + rr][k];
            float a0 = fmaf(zv.x, w0, acc[rr]);
            float a1 = fmaf(zv.y, w1, a0);
            float a2 = fmaf(zv.z, w2, a1);
            acc[rr] = fmaf(zv.w, w3, a2);
        }
    }
    #pragma unroll
    for (int rr = 0; rr < 16; ++rr) {
        size_t o = (tb + rg * 16 + rr) * D + j;
        h[o] += acc[rr];
    }
}

// out[t] = h[t] . outp_w + outp_b  (one wave per token)
__global__ __launch_bounds__(256) void k_final(
    const float* __restrict__ h, const float* __restrict__ outp_w,
    const float* __restrict__ outp_b, float* __restrict__ out)
{
    const int tid = threadIdx.x;
    const int lane = tid & 63;
    const size_t tok = (size_t)blockIdx.x * 4 + (tid >> 6);
    float a = h[tok * D + lane] * outp_w[lane] + h[tok * D + lane + 64] * outp_w[lane + 64];
    #pragma unroll
    for (int m = 1; m < 64; m <<= 1) a += __shfl_xor(a, m);
    if (lane == 0) out[tok] = a + outp_b[0];
}

extern "C" void kernel_launch(void* const* d_in, const int* in_sizes, int n_in,
                              void* d_out, int out_size, void* d_ws, size_t ws_size,
                              hipStream_t stream)
{
    const float* x      = (const float*)d_in[0];
    const float* inp_w  = (const float*)d_in[1];
    const float* inp_b  = (const float*)d_in[2];
    const float* outp_w = (const float*)d_in[3];
    const float* outp_b = (const float*)d_in[4];
    const float* ln_g   = (const float*)d_in[5];
    const float* ln_b   = (const float*)d_in[6];
    const float* in_w   = (const float*)d_in[7];
    const float* conv_w = (const float*)d_in[8];
    const float* conv_b = (const float*)d_in[9];
    const float* xp_w   = (const float*)d_in[10];
    const float* dp_w   = (const float*)d_in[11];
    const float* dp_b   = (const float*)d_in[12];
    const float* A_log  = (const float*)d_in[13];
    const float* Dp     = (const float*)d_in[14];
    const float* out_w  = (const float*)d_in[15];

    float* ws = (float*)d_ws;
    size_t off = 0;
    float* h      = ws + off; off += (size_t)NTOK * D;
    float* xc     = ws + off; off += (size_t)NTOK * D;
    float* resy   = ws + off; off += (size_t)NTOK * D;   // gate in, gated y out
    float* bc     = ws + off; off += (size_t)NTOK * 32;
    float* dlt    = ws + off; off += (size_t)NTOK * 8;
    float* in_wT  = ws + off; off += 4 * 128 * 256;
    float* xp_wT  = ws + off; off += 4 * 40 * 128;
    float* out_wT = ws + off; off += 4 * 128 * 128;
    float* A2     = ws + off; off += 4 * 128 * 16;
    if (ws_size < off * sizeof(float)) return;  // workspace too small -> fail visibly

    // prep
    k_transpose<<<(4 * 256 * 128 + 255) / 256, 256, 0, stream>>>(in_w, in_wT, 4, 256, 128);
    k_transpose<<<(4 * 40 * 128 + 255) / 256, 256, 0, stream>>>(xp_w, xp_wT, 4, 40, 128);
    k_transpose<<<(4 * 128 * 128 + 255) / 256, 256, 0, stream>>>(out_w, out_wT, 4, 128, 128);
    k_a2<<<(4 * 128 * 16 + 255) / 256, 256, 0, stream>>>(A_log, A2, 4 * 128 * 16);
    k_init_h<<<NTOK * D / 256, 256, 0, stream>>>(x, inp_w, inp_b, h);

    for (int l = 0; l < 4; ++l) {
        k_ln_inproj_conv<<<NTOK / 32, 256, 0, stream>>>(
            h, ln_g + l * 128, ln_b + l * 128, in_wT + l * 128 * 256,
            conv_w + l * 128 * 3, conv_b + l * 128, xc, resy);
        k_xproj<<<NTOK / 32, 256, 0, stream>>>(xc, xp_wT + l * 128 * 40, bc, dlt);
        k_scan<<<256, 256, 0, stream>>>(xc, bc, dlt, dp_w + l * 128 * 8, dp_b + l * 128,
                                        A2 + l * 128 * 16, Dp + l * 128, resy);
        k_outproj<<<NTOK / 32, 256, 0, stream>>>(resy, out_wT + l * 128 * 128, h);
    }
    k_final<<<NTOK / 4, 256, 0, stream>>>(h, outp_w, outp_b, (float*)d_out);
}

// Round 4
// 2403.272 us; speedup vs baseline: 1.2408x; 1.1183x over previous
//
#include <hip/hip_runtime.h>
#include <math.h>

#define D 128
#define NSTATE 16
#define DR 8
#define T_SEQ 1024
#define NTOK 131072  // 128 sequences * 1024 tokens
#define SEG 8        // segments per sequence (parallel scan)
#define SEGLEN 128   // T_SEQ / SEG
#define CH 16        // chunk (timesteps staged in LDS at once)

__device__ __forceinline__ float sigmoidf_(float x) { return 1.0f / (1.0f + __expf(-x)); }
__device__ __forceinline__ float softplusf_(float x) { return (x > 20.0f) ? x : log1pf(__expf(x)); }

// ---------------- prep kernels ----------------

// src (LB, J, K) -> dst (LB, K, J)
__global__ void k_transpose(const float* __restrict__ src, float* __restrict__ dst,
                            int LB, int J, int K) {
    int idx = blockIdx.x * blockDim.x + threadIdx.x;
    int total = LB * J * K;
    if (idx >= total) return;
    int l = idx / (J * K);
    int rem = idx - l * (J * K);
    int j = rem / K;
    int k = rem - j * K;
    dst[(size_t)l * J * K + (size_t)k * J + j] = src[idx];
}

// A2 = -exp(A_log) * log2(e)
__global__ void k_a2(const float* __restrict__ A_log, float* __restrict__ A2, int total) {
    int idx = blockIdx.x * blockDim.x + threadIdx.x;
    if (idx < total) A2[idx] = -__expf(A_log[idx]) * 1.44269504088896340736f;
}

// h[tok][d] = x[tok] * inp_w[d] + inp_b[d]
__global__ void k_init_h(const float* __restrict__ x, const float* __restrict__ inp_w,
                         const float* __restrict__ inp_b, float* __restrict__ h) {
    int idx = blockIdx.x * blockDim.x + threadIdx.x;
    int tok = idx >> 7;
    int d = idx & 127;
    h[idx] = x[tok] * inp_w[d] + inp_b[d];
}

// ---------------- per-layer kernels ----------------
// Fused LN + in_proj + causal depthwise conv(k=3) + SiLU.
__global__ __launch_bounds__(256) void k_ln_inproj_conv(
    const float* __restrict__ h, const float* __restrict__ ln_g, const float* __restrict__ ln_b,
    const float* __restrict__ in_wT,  // (128,256): in_wT[k][j] = in_w[j][k]
    const float* __restrict__ conv_w, const float* __restrict__ conv_b,
    float* __restrict__ xc, float* __restrict__ res)
{
    __shared__ float z[34][128];
    const int tid = threadIdx.x;
    const int tstart = blockIdx.x * 32;          // global central token start
    const int tin = tstart & (T_SEQ - 1);        // position within sequence

    const int wave = tid >> 6, lane = tid & 63;
    for (int r = wave; r < 34; r += 4) {
        int tr = tin + r - 2;
        if (tr < 0) { z[r][lane] = 0.f; z[r][lane + 64] = 0.f; continue; }
        size_t row = (size_t)(tstart + r - 2) * D;
        float a = h[row + lane];
        float b = h[row + lane + 64];
        float s = a + b, ss = a * a + b * b;
        #pragma unroll
        for (int m = 1; m < 64; m <<= 1) { s += __shfl_xor(s, m); ss += __shfl_xor(ss, m); }
        float mu = s * (1.0f / 128.0f);
        float var = ss * (1.0f / 128.0f) - mu * mu;
        float rstd = rsqrtf(var + 1e-5f);
        z[r][lane]      = (a - mu) * rstd * ln_g[lane]      + ln_b[lane];
        z[r][lane + 64] = (b - mu) * rstd * ln_g[lane + 64] + ln_b[lane + 64];
    }
    __syncthreads();

    float acc[34];
    #pragma unroll
    for (int r = 0; r < 34; ++r) acc[r] = 0.f;
    for (int k = 0; k < 128; k += 4) {
        float w0 = in_wT[(k + 0) * 256 + tid];
        float w1 = in_wT[(k + 1) * 256 + tid];
        float w2 = in_wT[(k + 2) * 256 + tid];
        float w3 = in_wT[(k + 3) * 256 + tid];
        #pragma unroll
        for (int r = 0; r < 34; ++r) {
            float4 zv = *(const float4*)&z[r][k];
            float a0 = fmaf(zv.x, w0, acc[r]);
            float a1 = fmaf(zv.y, w1, a0);
            float a2 = fmaf(zv.z, w2, a1);
            acc[r] = fmaf(zv.w, w3, a2);
        }
    }

    if (tid < 128) {
        float c0 = conv_w[tid * 3 + 0], c1 = conv_w[tid * 3 + 1], c2 = conv_w[tid * 3 + 2];
        float cb = conv_b[tid];
        #pragma unroll
        for (int s = 0; s < 32; ++s) {
            float v = acc[s] * c0 + acc[s + 1] * c1 + acc[s + 2] * c2 + cb;
            v = v * sigmoidf_(v);
            xc[(size_t)(tstart + s) * D + tid] = v;
        }
    } else {
        int jj = tid - 128;
        #pragma unroll
        for (int s = 0; s < 32; ++s)
            res[(size_t)(tstart + s) * D + jj] = acc[s + 2];
    }
}

// x_proj: per token, dlt[0..7] and bc[0..31] = xc @ xp_w.T split.
__global__ __launch_bounds__(256) void k_xproj(
    const float* __restrict__ xc, const float* __restrict__ xp_wT,
    float* __restrict__ bc, float* __restrict__ dlt)
{
    __shared__ float xcs[32][128];
    const int tid = threadIdx.x;
    const size_t tb = (size_t)blockIdx.x * 32;
    #pragma unroll
    for (int i = 0; i < 4; ++i) {
        int idx = tid + i * 256;
        int row = idx >> 5, c4 = idx & 31;
        *(float4*)&xcs[row][c4 * 4] = *(const float4*)&xc[(tb + row) * D + c4 * 4];
    }
    __syncthreads();
    const int j = tid & 63, rg = tid >> 6;
    if (j < 40) {
        float acc[8] = {0.f, 0.f, 0.f, 0.f, 0.f, 0.f, 0.f, 0.f};
        for (int k = 0; k < 128; k += 4) {
            float w0 = xp_wT[(k + 0) * 40 + j];
            float w1 = xp_wT[(k + 1) * 40 + j];
            float w2 = xp_wT[(k + 2) * 40 + j];
            float w3 = xp_wT[(k + 3) * 40 + j];
            #pragma unroll
            for (int rr = 0; rr < 8; ++rr) {
                float4 zv = *(const float4*)&xcs[rg * 8 + rr][k];
                float a0 = fmaf(zv.x, w0, acc[rr]);
                float a1 = fmaf(zv.y, w1, a0);
                float a2 = fmaf(zv.z, w2, a1);
                acc[rr] = fmaf(zv.w, w3, a2);
            }
        }
        if (j < 8) {
            #pragma unroll
            for (int rr = 0; rr < 8; ++rr)
                dlt[(tb + rg * 8 + rr) * 8 + j] = acc[rr];
        } else {
            #pragma unroll
            for (int rr = 0; rr < 8; ++rr)
                bc[(tb + rg * 8 + rr) * 32 + (j - 8)] = acc[rr];
        }
    }
}

// ---- chunk-parallel selective scan ----
// Pass 1: per-segment scan from x=0. Emits F (state at segment end) and
// P = exp2(A2 * sum(dt)) (segment decay). Grid: 128 seq x 8 seg x 2 d-halves
// = 2048 blocks of 256 threads (64 d x 4 n-quads, 4 states each).
__global__ __launch_bounds__(256) void k_scan1(
    const float* __restrict__ xc, const float* __restrict__ bc,
    const float* __restrict__ dlt,
    const float* __restrict__ dp_w, const float* __restrict__ dp_b,
    const float* __restrict__ A2,
    float* __restrict__ Pbuf, float* __restrict__ Fbuf)
{
    __shared__ float u_l[CH][64];
    __shared__ float bc_l[CH][32];
    __shared__ float dlt_l[CH][8];
    __shared__ float dl_l[CH][64];
    __shared__ float dpw_s[64][9];
    __shared__ float dpb_s[64];

    const int tid = threadIdx.x;
    const int bt = blockIdx.x >> 4;
    const int seg = (blockIdx.x >> 1) & 7;
    const int d0 = (blockIdx.x & 1) * 64;
    const int dd = tid >> 2, q = tid & 3;
    const int d = d0 + dd;

    #pragma unroll
    for (int i = 0; i < 2; ++i) {
        int idx = tid + i * 256;
        dpw_s[idx >> 3][idx & 7] = dp_w[(d0 + (idx >> 3)) * 8 + (idx & 7)];
    }
    if (tid < 64) dpb_s[tid] = dp_b[d0 + tid];
    float A2q[4];
    #pragma unroll
    for (int jn = 0; jn < 4; ++jn) A2q[jn] = A2[d * NSTATE + q * 4 + jn];
    float x0 = 0.f, x1 = 0.f, x2 = 0.f, x3 = 0.f, S = 0.f;

    const size_t segbase = (size_t)bt * T_SEQ + (size_t)seg * SEGLEN;
    float4 su, sbc, sdl;
    su = *(const float4*)&xc[(segbase + (tid >> 4)) * D + d0 + (tid & 15) * 4];
    if (tid < 128) sbc = *(const float4*)&bc[(segbase + (tid >> 3)) * 32 + (tid & 7) * 4];
    if (tid < 32)  sdl = *(const float4*)&dlt[(segbase + (tid >> 1)) * 8 + (tid & 1) * 4];

    for (int c = 0; c < SEGLEN / CH; ++c) {
        *(float4*)&u_l[tid >> 4][(tid & 15) * 4] = su;
        if (tid < 128) *(float4*)&bc_l[tid >> 3][(tid & 7) * 4] = sbc;
        if (tid < 32)  *(float4*)&dlt_l[tid >> 1][(tid & 1) * 4] = sdl;
        __syncthreads();
        if (c + 1 < SEGLEN / CH) {
            const size_t nb = segbase + (size_t)(c + 1) * CH;
            su = *(const float4*)&xc[(nb + (tid >> 4)) * D + d0 + (tid & 15) * 4];
            if (tid < 128) sbc = *(const float4*)&bc[(nb + (tid >> 3)) * 32 + (tid & 7) * 4];
            if (tid < 32)  sdl = *(const float4*)&dlt[(nb + (tid >> 1)) * 8 + (tid & 1) * 4];
        }
        // delta: col = lane (bank-clean), 4 rows per thread
        {
            int col = tid & 63;
            #pragma unroll
            for (int i = 0; i < 4; ++i) {
                int row = (tid >> 6) + 4 * i;
                float v = dpb_s[col];
                #pragma unroll
                for (int r = 0; r < DR; ++r) v = fmaf(dlt_l[row][r], dpw_s[col][r], v);
                dl_l[row][col] = softplusf_(v);
            }
        }
        __syncthreads();
        #pragma unroll
        for (int tl = 0; tl < CH; ++tl) {
            float dt = dl_l[tl][dd];
            float uv = u_l[tl][dd];
            float duv = dt * uv;
            S += dt;
            float4 Bq = *(const float4*)&bc_l[tl][q * 4];
            x0 = fmaf(exp2f(dt * A2q[0]), x0, duv * Bq.x);
            x1 = fmaf(exp2f(dt * A2q[1]), x1, duv * Bq.y);
            x2 = fmaf(exp2f(dt * A2q[2]), x2, duv * Bq.z);
            x3 = fmaf(exp2f(dt * A2q[3]), x3, duv * Bq.w);
        }
        __syncthreads();
    }
    const size_t o = ((size_t)(bt * SEG + seg) * D + d) * NSTATE + q * 4;
    *(float4*)&Fbuf[o] = make_float4(x0, x1, x2, x3);
    *(float4*)&Pbuf[o] = make_float4(exp2f(A2q[0] * S), exp2f(A2q[1] * S),
                                     exp2f(A2q[2] * S), exp2f(A2q[3] * S));
}

// Fix-up: serial combine of segment summaries -> x_init per segment.
// One thread per (seq, d, n) chain: 262144 threads.
__global__ __launch_bounds__(256) void k_fix(
    const float* __restrict__ P, const float* __restrict__ F, float* __restrict__ xinit)
{
    int gid = blockIdx.x * 256 + threadIdx.x;
    int seq = gid >> 11, dn = gid & 2047;
    float xi = 0.f;
    #pragma unroll
    for (int s = 0; s < SEG; ++s) {
        size_t idx = (size_t)(seq * SEG + s) * 2048 + dn;
        xinit[idx] = xi;
        xi = fmaf(P[idx], xi, F[idx]);
    }
}

// Pass 2: re-scan each segment from x_init; full y = C.x + u*Dp, gated, direct store.
__global__ __launch_bounds__(256) void k_scan2(
    const float* __restrict__ xc, const float* __restrict__ bc,
    const float* __restrict__ dlt,
    const float* __restrict__ dp_w, const float* __restrict__ dp_b,
    const float* __restrict__ A2, const float* __restrict__ Dp,
    const float* __restrict__ xinit,
    float* __restrict__ resy)   // in: gate, out: gated y
{
    __shared__ float u_l[CH][64];
    __shared__ float r_l[CH][64];
    __shared__ float bc_l[CH][32];
    __shared__ float dlt_l[CH][8];
    __shared__ float dl_l[CH][64];
    __shared__ float dpw_s[64][9];
    __shared__ float dpb_s[64];

    const int tid = threadIdx.x;
    const int bt = blockIdx.x >> 4;
    const int seg = (blockIdx.x >> 1) & 7;
    const int d0 = (blockIdx.x & 1) * 64;
    const int dd = tid >> 2, q = tid & 3;
    const int d = d0 + dd;

    #pragma unroll
    for (int i = 0; i < 2; ++i) {
        int idx = tid + i * 256;
        dpw_s[idx >> 3][idx & 7] = dp_w[(d0 + (idx >> 3)) * 8 + (idx & 7)];
    }
    if (tid < 64) dpb_s[tid] = dp_b[d0 + tid];
    float A2q[4];
    #pragma unroll
    for (int jn = 0; jn < 4; ++jn) A2q[jn] = A2[d * NSTATE + q * 4 + jn];
    const float Dpd = Dp[d];
    float4 xiv = *(const float4*)&xinit[((size_t)(bt * SEG + seg) * D + d) * NSTATE + q * 4];
    float x0 = xiv.x, x1 = xiv.y, x2 = xiv.z, x3 = xiv.w;

    const size_t segbase = (size_t)bt * T_SEQ + (size_t)seg * SEGLEN;
    float4 su, sr, sbc, sdl;
    su = *(const float4*)&xc[(segbase + (tid >> 4)) * D + d0 + (tid & 15) * 4];
    sr = *(const float4*)&resy[(segbase + (tid >> 4)) * D + d0 + (tid & 15) * 4];
    if (tid < 128) sbc = *(const float4*)&bc[(segbase + (tid >> 3)) * 32 + (tid & 7) * 4];
    if (tid < 32)  sdl = *(const float4*)&dlt[(segbase + (tid >> 1)) * 8 + (tid & 1) * 4];

    for (int c = 0; c < SEGLEN / CH; ++c) {
        const size_t tb = segbase + (size_t)c * CH;
        *(float4*)&u_l[tid >> 4][(tid & 15) * 4] = su;
        *(float4*)&r_l[tid >> 4][(tid & 15) * 4] = sr;
        if (tid < 128) *(float4*)&bc_l[tid >> 3][(tid & 7) * 4] = sbc;
        if (tid < 32)  *(float4*)&dlt_l[tid >> 1][(tid & 1) * 4] = sdl;
        __syncthreads();
        if (c + 1 < SEGLEN / CH) {
            const size_t nb = tb + CH;
            su = *(const float4*)&xc[(nb + (tid >> 4)) * D + d0 + (tid & 15) * 4];
            sr = *(const float4*)&resy[(nb + (tid >> 4)) * D + d0 + (tid & 15) * 4];
            if (tid < 128) sbc = *(const float4*)&bc[(nb + (tid >> 3)) * 32 + (tid & 7) * 4];
            if (tid < 32)  sdl = *(const float4*)&dlt[(nb + (tid >> 1)) * 8 + (tid & 1) * 4];
        }
        {
            int col = tid & 63;
            #pragma unroll
            for (int i = 0; i < 4; ++i) {
                int row = (tid >> 6) + 4 * i;
                float v = dpb_s[col];
                #pragma unroll
                for (int r = 0; r < DR; ++r) v = fmaf(dlt_l[row][r], dpw_s[col][r], v);
                dl_l[row][col] = softplusf_(v);
            }
        }
        __syncthreads();
        #pragma unroll
        for (int tl = 0; tl < CH; ++tl) {
            float dt = dl_l[tl][dd];
            float uv = u_l[tl][dd];
            float duv = dt * uv;
            float4 Bq = *(const float4*)&bc_l[tl][q * 4];
            float4 Cq = *(const float4*)&bc_l[tl][16 + q * 4];
            x0 = fmaf(exp2f(dt * A2q[0]), x0, duv * Bq.x);
            x1 = fmaf(exp2f(dt * A2q[1]), x1, duv * Bq.y);
            x2 = fmaf(exp2f(dt * A2q[2]), x2, duv * Bq.z);
            x3 = fmaf(exp2f(dt * A2q[3]), x3, duv * Bq.w);
            float p = x0 * Cq.x;
            p = fmaf(x1, Cq.y, p);
            p = fmaf(x2, Cq.z, p);
            p = fmaf(x3, Cq.w, p);
            p += __shfl_xor(p, 1);
            p += __shfl_xor(p, 2);
            if (q == 0) {
                float g = r_l[tl][dd];
                resy[(tb + tl) * D + d] = (p + uv * Dpd) * (g * sigmoidf_(g));
            }
        }
        __syncthreads();
    }
}

// out_proj + residual: h[t] += y[t] @ out_w.T   (y already gated)
__global__ __launch_bounds__(256) void k_outproj(
    const float* __restrict__ y, const float* __restrict__ out_wT, float* __restrict__ h)
{
    __shared__ float ys[32][128];
    const int tid = threadIdx.x;
    const size_t tb = (size_t)blockIdx.x * 32;
    #pragma unroll
    for (int i = 0; i < 4; ++i) {
        int idx = tid + i * 256;
        int row = idx >> 5, c4 = idx & 31;
        *(float4*)&ys[row][c4 * 4] = *(const float4*)&y[(tb + row) * D + c4 * 4];
    }
    __syncthreads();
    const int j = tid & 127, rg = tid >> 7;
    float acc[16];
    #pragma unroll
    for (int rr = 0; rr < 16; ++rr) acc[rr] = 0.f;
    for (int k = 0; k < 128; k += 4) {
        float w0 = out_wT[(k + 0) * 128 + j];
        float w1 = out_wT[(k + 1) * 128 + j];
        float w2 = out_wT[(k + 2) * 128 + j];
        float w3 = out_wT[(k + 3) * 128 + j];
        #pragma unroll
        for (int rr = 0; rr < 16; ++rr) {
            float4 zv = *(const float4*)&ys[rg * 16 + rr][k];
            float a0 = fmaf(zv.x, w0, acc[rr]);
            float a1 = fmaf(zv.y, w1, a0);
            float a2 = fmaf(zv.z, w2, a1);
            acc[rr] = fmaf(zv.w, w3, a2);
        }
    }
    #pragma unroll
    for (int rr = 0; rr < 16; ++rr) {
        size_t o = (tb + rg * 16 + rr) * D + j;
        h[o] += acc[rr];
    }
}

// out[t] = h[t] . outp_w + outp_b  (one wave per token)
__global__ __launch_bounds__(256) void k_final(
    const float* __restrict__ h, const float* __restrict__ outp_w,
    const float* __restrict__ outp_b, float* __restrict__ out)
{
    const int tid = threadIdx.x;
    const int lane = tid & 63;
    const size_t tok = (size_t)blockIdx.x * 4 + (tid >> 6);
    float a = h[tok * D + lane] * outp_w[lane] + h[tok * D + lane + 64] * outp_w[lane + 64];
    #pragma unroll
    for (int m = 1; m < 64; m <<= 1) a += __shfl_xor(a, m);
    if (lane == 0) out[tok] = a + outp_b[0];
}

extern "C" void kernel_launch(void* const* d_in, const int* in_sizes, int n_in,
                              void* d_out, int out_size, void* d_ws, size_t ws_size,
                              hipStream_t stream)
{
    const float* x      = (const float*)d_in[0];
    const float* inp_w  = (const float*)d_in[1];
    const float* inp_b  = (const float*)d_in[2];
    const float* outp_w = (const float*)d_in[3];
    const float* outp_b = (const float*)d_in[4];
    const float* ln_g   = (const float*)d_in[5];
    const float* ln_b   = (const float*)d_in[6];
    const float* in_w   = (const float*)d_in[7];
    const float* conv_w = (const float*)d_in[8];
    const float* conv_b = (const float*)d_in[9];
    const float* xp_w   = (const float*)d_in[10];
    const float* dp_w   = (const float*)d_in[11];
    const float* dp_b   = (const float*)d_in[12];
    const float* A_log  = (const float*)d_in[13];
    const float* Dp     = (const float*)d_in[14];
    const float* out_w  = (const float*)d_in[15];

    float* ws = (float*)d_ws;
    size_t off = 0;
    float* h      = ws + off; off += (size_t)NTOK * D;
    float* xc     = ws + off; off += (size_t)NTOK * D;
    float* resy   = ws + off; off += (size_t)NTOK * D;   // gate in, gated y out
    float* bc     = ws + off; off += (size_t)NTOK * 32;
    float* dlt    = ws + off; off += (size_t)NTOK * 8;
    float* Pbuf   = ws + off; off += 128 * SEG * 2048;
    float* Fbuf   = ws + off; off += 128 * SEG * 2048;
    float* xinit  = ws + off; off += 128 * SEG * 2048;
    float* in_wT  = ws + off; off += 4 * 128 * 256;
    float* xp_wT  = ws + off; off += 4 * 40 * 128;
    float* out_wT = ws + off; off += 4 * 128 * 128;
    float* A2     = ws + off; off += 4 * 128 * 16;
    if (ws_size < off * sizeof(float)) return;  // workspace too small -> fail visibly

    // prep
    k_transpose<<<(4 * 256 * 128 + 255) / 256, 256, 0, stream>>>(in_w, in_wT, 4, 256, 128);
    k_transpose<<<(4 * 40 * 128 + 255) / 256, 256, 0, stream>>>(xp_w, xp_wT, 4, 40, 128);
    k_transpose<<<(4 * 128 * 128 + 255) / 256, 256, 0, stream>>>(out_w, out_wT, 4, 128, 128);
    k_a2<<<(4 * 128 * 16 + 255) / 256, 256, 0, stream>>>(A_log, A2, 4 * 128 * 16);
    k_init_h<<<NTOK * D / 256, 256, 0, stream>>>(x, inp_w, inp_b, h);

    for (int l = 0; l < 4; ++l) {
        k_ln_inproj_conv<<<NTOK / 32, 256, 0, stream>>>(
            h, ln_g + l * 128, ln_b + l * 128, in_wT + l * 128 * 256,
            conv_w + l * 128 * 3, conv_b + l * 128, xc, resy);
        k_xproj<<<NTOK / 32, 256, 0, stream>>>(xc, xp_wT + l * 128 * 40, bc, dlt);
        k_scan1<<<2048, 256, 0, stream>>>(xc, bc, dlt, dp_w + l * 128 * 8, dp_b + l * 128,
                                          A2 + l * 128 * 16, Pbuf, Fbuf);
        k_fix<<<1024, 256, 0, stream>>>(Pbuf, Fbuf, xinit);
        k_scan2<<<2048, 256, 0, stream>>>(xc, bc, dlt, dp_w + l * 128 * 8, dp_b + l * 128,
                                          A2 + l * 128 * 16, Dp + l * 128, xinit, resy);
        k_outproj<<<NTOK / 32, 256, 0, stream>>>(resy, out_wT + l * 128 * 128, h);
    }
    k_final<<<NTOK / 4, 256, 0, stream>>>(h, outp_w, outp_b, (float*)d_out);
}